// Round 14
// baseline (121.327 us; speedup 1.0000x reference)
//
#include <hip/hip_runtime.h>
#include <math.h>

// Problem constants (fixed by reference setup_inputs): pred [32,1,512,512] f32
#define IMG_W 512
#define IMG_H 512
#define HW (IMG_W * IMG_H)      // 262144 = 2^18
#define LOGHW 18
#define NIMG 32
#define NTOT (NIMG * HW)        // 8388608
#define CPI 64                  // stat-chunks per image (4096 px each)
#define NSCHUNK (NIMG * CPI)    // 2048
// 32x32 tiles, one WAVE per tile (zero-barrier CCL)
#define STILE 32
#define TPI2 256                // 16x16 tiles per image
#define NTILE2 (NIMG * TPI2)    // 8192 tiles
#define WPB 4                   // waves (tiles) per block
#define NBLK2 (NTILE2 / WPB)    // 2048 blocks
#define EDGE2 (NTILE2 * 32)     // 262144 entries per edge direction (1 MB)
#define PPI 480                 // tile-pairs per image (240 vert + 240 horiz)
#define NPAIR2 (NIMG * PPI)     // 15360 pairs x 32 positions
// NOTE (R6): no wide cross-kernel counter handshakes (2048-way = 56us dead).
// NOTE (R12): no big register prefetch — VGPR 16->44 halved occupancy, +11us.
// NOTE (R13): R8 structure = 120us; k_local pinned 44-47us across 3 variants
// with 4 phase barriers. This round: wave-per-tile, ZERO barriers.

// ---------------- lock-free min-index union-find ----------------------------
__device__ __forceinline__ void uf_unite(int* L, int a, int b) {
    while (true) {
        int p = ((volatile int*)L)[a];
        while (p != a) { a = p; p = ((volatile int*)L)[a]; }
        p = ((volatile int*)L)[b];
        while (p != b) { b = p; p = ((volatile int*)L)[b]; }
        if (a == b) return;
        if (a < b) { int t = a; a = b; b = t; }  // a > b
        int old = atomicMin(&L[a], b);
        if (old == a) return;
        a = old;
    }
}

// ---------------- K1: zero-barrier wave-per-tile CCL + base BCE + edges -----
// One WAVE per 32x32 tile (4 waves/block, private LDS slices, no
// __syncthreads anywhere except the final BCE reduce). Lanes 0-31 handle the
// even row of a row-pair, lanes 32-63 the odd row; one __ballot gives both
// rows' fg masks as wave-uniform scalars. Run-start entries only in LDS;
// vertical contact-run unites computed from register masks via clz. Local
// raster order within a tile is order-isomorphic to global raster order, so
// min-index roots are exact (same argument as 64x64 tiles).
__global__ __launch_bounds__(256) void k_local(const float* __restrict__ pred,
                                               int* __restrict__ L,
                                               float* __restrict__ partials,
                                               int* __restrict__ edges,
                                               unsigned int* __restrict__ counter) {
    __shared__ int lab[WPB * 1024];            // 16 KB, 4 KB per wave
    __shared__ unsigned int mskS[WPB * 32];    // 512 B row masks
    __shared__ float wsum[WPB];
    int tid = threadIdx.x;
    int lane = tid & 63, wave = tid >> 6;
    int tileG = blockIdx.x * WPB + wave;
    int img = tileG >> 8;
    int t = tileG & 255;
    int ty = t >> 4, tx = t & 15;
    int baseLocal = (ty * STILE) * IMG_W + tx * STILE;  // image-local origin
    const float* pi = pred + ((size_t)img << LOGHW);
    int* Li = L + ((size_t)img << LOGHW);
    int* mylab = lab + wave * 1024;
    unsigned int* mymsk = mskS + wave * 32;
    int sub = lane >> 5;       // 0 = even row of pair, 1 = odd row
    int q = lane & 31;         // column within tile
    unsigned int mle = 0xFFFFFFFFu >> (31 - q);

    float acc = 0.0f;
    unsigned int mprev = 0;    // previous iteration's odd-row mask (uniform)
    for (int i = 0; i < 16; i++) {
        int row = 2 * i + sub;
        float p = pi[baseLocal + row * IMG_W + q];
        acc += fmaxf(__logf(1.0f - p), -100.0f);   // 1-p exact for p>=0.5
        unsigned long long bal = __ballot(p >= 0.5f);
        unsigned int m0 = (unsigned int)bal;            // row 2i
        unsigned int m1 = (unsigned int)(bal >> 32);    // row 2i+1
        if (lane == 0)  mymsk[2 * i] = m0;
        if (lane == 32) mymsk[2 * i + 1] = m1;
        // run-start init (lab touched only at starts)
        unsigned int m = sub ? m1 : m0;
        unsigned int st = m & ~(m << 1);
        if ((st >> q) & 1u) mylab[row * STILE + q] = row * STILE + q;
        // vertical unites: lanes 0-31 do (2i-1,2i); lanes 32-63 do (2i,2i+1)
        unsigned int mup = sub ? m0 : mprev;
        unsigned int mdn = sub ? m1 : m0;
        int rup = 2 * i - 1 + sub;
        unsigned int cu = mup & mdn;
        unsigned int cs = cu & ~(cu << 1);        // contact-run starts
        if ((cs >> q) & 1u) {
            unsigned int stup = mup & ~(mup << 1);
            unsigned int stdn = mdn & ~(mdn << 1);
            int a = rup * STILE + (31 - __builtin_clz(stup & mle));
            int b = (rup + 1) * STILE + (31 - __builtin_clz(stdn & mle));
            uf_unite(mylab, a, b);
        }
        mprev = m1;
    }
    // ---- run-starts chase to root (path halving + full compress), no bar ---
    for (int i = 0; i < 16; i++) {
        int row = 2 * i + sub;
        unsigned int m = mymsk[row];
        unsigned int st = m & ~(m << 1);
        if ((st >> q) & 1u) {
            int idx = row * STILE + q;
            int x = idx, p = mylab[x];
            while (p != x) {
                int g = mylab[p];
                mylab[x] = g;        // halving: benign race, ancestors only
                x = g;
                p = mylab[x];
            }
            mylab[idx] = x;
        }
    }
    // ---- per-px root via register clz + ONE lab read; write L (int4) -------
#pragma unroll
    for (int j = 0; j < 4; j++) {
        int idx = (j * 64 + lane) * 4;
        int row = idx >> 5, c0 = idx & 31;
        unsigned int m = mymsk[row];
        unsigned int st = m & ~(m << 1);
        int4 o;
        int* op = (int*)&o;
#pragma unroll
        for (int k = 0; k < 4; k++) {
            int c = c0 + k;
            if (!((m >> c) & 1u)) op[k] = -1;
            else {
                unsigned int pre = st & (0xFFFFFFFFu >> (31 - c));
                int s = row * STILE + (31 - __builtin_clz(pre));
                int r = mylab[s];                // start entries = roots now
                op[k] = baseLocal + (r >> 5) * IMG_W + (r & 31);
            }
        }
        *(int4*)(Li + baseLocal + row * IMG_W + c0) = o;
    }
    // ---- edge export: 4 dirs x 32 entries, 2 per lane ----------------------
#pragma unroll
    for (int pass = 0; pass < 2; pass++) {
        int e = pass * 2 + sub;                  // 0=T,1=B then 2=L,3=R
        int val = -1;
        if (e == 0) {
            unsigned int m = mymsk[0];
            if ((m >> q) & 1u) {
                unsigned int st = m & ~(m << 1);
                int s = 31 - __builtin_clz(st & mle);
                int r = mylab[s];
                val = baseLocal + (r >> 5) * IMG_W + (r & 31);
            }
        } else if (e == 1) {
            unsigned int m = mymsk[31];
            if ((m >> q) & 1u) {
                unsigned int st = m & ~(m << 1);
                int s = 31 * STILE + (31 - __builtin_clz(st & mle));
                int r = mylab[s];
                val = baseLocal + (r >> 5) * IMG_W + (r & 31);
            }
        } else if (e == 2) {                     // left col: bit0 is a start
            unsigned int m = mymsk[q];
            if (m & 1u) {
                int r = mylab[q * STILE];
                val = baseLocal + (r >> 5) * IMG_W + (r & 31);
            }
        } else {                                 // right col 31
            unsigned int m = mymsk[q];
            if ((m >> 31) & 1u) {
                unsigned int st = m & ~(m << 1);
                int s = q * STILE + (31 - __builtin_clz(st));
                int r = mylab[s];
                val = baseLocal + (r >> 5) * IMG_W + (r & 31);
            }
        }
        edges[e * EDGE2 + tileG * 32 + q] = val;
    }
    // ---- base BCE: wave shfl reduce; ONE barrier in the whole kernel -------
#pragma unroll
    for (int off = 32; off > 0; off >>= 1)
        acc += __shfl_down(acc, off, 64);
    if (lane == 0) wsum[wave] = acc;
    __syncthreads();
    if (tid == 0)
        partials[blockIdx.x] = wsum[0] + wsum[1] + wsum[2] + wsum[3];
    if (blockIdx.x == 0 && tid == 0) *counter = 0u;   // ws is 0xAA-poisoned
}

// ---------------- K2: cross-tile border unites from compact edges -----------
// Two 32-position pairs per wave (pairs never straddle images or v/h kinds:
// 480 and 240 are even). Ballot-compress per 32-bit half — bit 32's carry
// from bit 31 is masked out so runs can't link across the pair boundary.
__global__ __launch_bounds__(256) void k_border(const int* __restrict__ edges,
                                                int* __restrict__ L) {
    int gid = blockIdx.x * blockDim.x + threadIdx.x;
    int w = gid >> 6;
    int lane = gid & 63;
    int pair = w * 2 + (lane >> 5);
    int q = lane & 31;
    int img = pair / PPI;                // wave-uniform
    int r = pair - img * PPI;
    int a, b;
    if (r < 240) {                       // vertical: (ty,tx)-(ty,tx+1)
        int ty = r / 15, tx = r - ty * 15;
        int tl = img * TPI2 + ty * 16 + tx;
        a = edges[3 * EDGE2 + tl * 32 + q];         // right edge of left
        b = edges[2 * EDGE2 + (tl + 1) * 32 + q];   // left edge of right
    } else {                             // horizontal: (ty,tx)-(ty+1,tx)
        int r2 = r - 240;
        int ty = r2 >> 4, tx = r2 & 15;
        int tu = img * TPI2 + ty * 16 + tx;
        a = edges[1 * EDGE2 + tu * 32 + q];         // bottom edge of upper
        b = edges[0 * EDGE2 + (tu + 16) * 32 + q];  // top edge of lower
    }
    bool c = (a >= 0) && (b >= 0);
    unsigned long long cb = __ballot(c);
    unsigned long long shifted = (cb << 1) & ~(1ULL << 32);  // no cross-pair
    unsigned long long cs = cb & ~shifted;                   // contact starts
    if ((cs >> lane) & 1ULL)
        uf_unite(L + ((size_t)img << LOGHW), a, b);
}

// ---------------- K3: per-chunk stats (4096 px): roots, maxRoot, minFg ------
__global__ __launch_bounds__(256) void k_stats(const int* __restrict__ L,
                                               int* __restrict__ cntArr,
                                               int* __restrict__ maxArr,
                                               int* __restrict__ minArr) {
    __shared__ int s1[256], s2[256], s3[256];
    int chunk = blockIdx.x;
    int img = chunk >> 6;
    int baseL = (chunk & 63) * 4096;             // image-local
    const int* Li = L + ((size_t)img << LOGHW);
    int t = threadIdx.x;
    int cnt = 0, mx = -1, mn = HW;
#pragma unroll
    for (int j = 0; j < 4; j++) {
        int off = baseL + (t + j * 256) * 4;
        int4 l4 = *(const int4*)(Li + off);
        const int* lp = (const int*)&l4;
#pragma unroll
        for (int k = 0; k < 4; k++) {
            int local = off + k;
            int p = lp[k];
            bool root = (p == local);
            cnt += root ? 1 : 0;
            if (root && local > mx) mx = local;
            if (p >= 0 && local >= 1 && local < mn) mn = local;
        }
    }
    s1[t] = cnt; s2[t] = mx; s3[t] = mn;
    __syncthreads();
    for (int s = 128; s > 0; s >>= 1) {
        if (t < s) {
            s1[t] += s1[t + s];
            s2[t] = max(s2[t], s2[t + s]);
            s3[t] = min(s3[t], s3[t + s]);
        }
        __syncthreads();
    }
    if (t == 0) { cntArr[chunk] = s1[0]; maxArr[chunk] = s2[0]; minArr[chunk] = s3[0]; }
}

// ---------------- K4: fused rv + correction + final reduce ------------------
__global__ __launch_bounds__(256) void k_tail(const int* __restrict__ cntArr,
                                              const int* __restrict__ maxArr,
                                              const int* __restrict__ minArr,
                                              const int* __restrict__ L,
                                              const float* __restrict__ pred,
                                              const float* __restrict__ partials,
                                              float* __restrict__ corr,
                                              unsigned int* __restrict__ counter,
                                              float* __restrict__ out) {
    __shared__ int sc[256], sm[256], sn[256];
    __shared__ int sel_chunk, sel_base, result;
    __shared__ float sf[256];
    __shared__ double sd[256];
    __shared__ unsigned int oldc;
    int img = blockIdx.x, t = threadIdx.x;
    const int* Li = L + ((size_t)img << LOGHW);
    int cnt = (t < CPI) ? cntArr[img * CPI + t] : 0;
    sc[t] = cnt;
    sm[t] = (t < CPI) ? maxArr[img * CPI + t] : -1;
    sn[t] = (t < CPI) ? minArr[img * CPI + t] : HW;
    if (t == 0) result = -2;
    __syncthreads();
    for (int off = 1; off < 256; off <<= 1) {    // inclusive scan of counts
        int v2 = (t >= off) ? sc[t - off] : 0;
        __syncthreads();
        sc[t] += v2;
        __syncthreads();
    }
    int num = sc[255];
    int inc = sc[t], exc = inc - cnt;
    for (int s = 128; s > 0; s >>= 1) {
        if (t < s) { sm[t] = max(sm[t], sm[t + s]); sn[t] = min(sn[t], sn[t + s]); }
        __syncthreads();
    }
    int last_root = sm[0], minFg = sn[0];
    int v;
    if (last_root >= 1) v = last_root;
    else if (last_root == 0) v = (minFg < HW) ? minFg : 1;
    else v = 1;
    if (v >= 1 && v <= num) {            // block-uniform branch
        if (exc < v && v <= inc) { sel_chunk = t; sel_base = exc; }
        __syncthreads();
        int c = sel_chunk, base = sel_base;
        int baseL = c * 4096;
        int f[16];
        int sum = 0;
#pragma unroll
        for (int j = 0; j < 4; j++) {
            int off = baseL + t * 16 + j * 4;
            int4 l4 = *(const int4*)(Li + off);
            const int* lp = (const int*)&l4;
#pragma unroll
            for (int k = 0; k < 4; k++) {
                f[j * 4 + k] = (lp[k] == off + k) ? 1 : 0;
                sum += f[j * 4 + k];
            }
        }
        __syncthreads();
        sc[t] = sum;
        __syncthreads();
        for (int off = 1; off < 256; off <<= 1) {
            int v2 = (t >= off) ? sc[t - off] : 0;
            __syncthreads();
            sc[t] += v2;
            __syncthreads();
        }
        int exc2 = sc[t] - sum;
        int need = v - base;
        if (exc2 < need && need <= sc[t]) {
            int run = exc2;
#pragma unroll
            for (int k = 0; k < 16; k++) {
                run += f[k];
                if (run == need) { result = baseL + t * 16 + k; break; }
            }
        }
        __syncthreads();
    } else {
        __syncthreads();
    }
    int rvv = result;
    float blocksum = 0.0f;
    if (rvv >= 0) {                      // rare path: scan whole image
        const float* pi = pred + ((size_t)img << LOGHW);
        float acc = 0.0f;
        for (int it = 0; it < HW / 1024; it++) {
            int off = it * 1024 + t * 4;
            float4 p4 = *(const float4*)(pi + off);
            int4 l4 = *(const int4*)(Li + off);
            const float* pp = (const float*)&p4;
            const int* lp = (const int*)&l4;
#pragma unroll
            for (int k = 0; k < 4; k++) {
                int p = lp[k];
                if (p < 0) continue;
                int x = p, q = Li[x];
                while (q != x) { x = q; q = Li[x]; }
                if (x == rvv) {
                    float pr = pp[k];
                    acc += fmaxf(__logf(pr), -100.0f)
                         - fmaxf(__logf(1.0f - pr), -100.0f);
                }
            }
        }
        sf[t] = acc;
        __syncthreads();
        for (int s = 128; s > 0; s >>= 1) {
            if (t < s) sf[t] += sf[t + s];
            __syncthreads();
        }
        blocksum = sf[0];
    }
    if (t == 0) {
        __hip_atomic_store(&corr[img], blocksum, __ATOMIC_RELAXED,
                           __HIP_MEMORY_SCOPE_AGENT);
        oldc = __hip_atomic_fetch_add(counter, 1u, __ATOMIC_ACQ_REL,
                                      __HIP_MEMORY_SCOPE_AGENT);
    }
    __syncthreads();
    if (oldc != NIMG - 1) return;
    // ---- last of 32 blocks: final reduce -----------------------------------
    double acc = 0.0;
#pragma unroll
    for (int j = 0; j < 8; j++) acc += (double)partials[t + j * 256];
    if (t < NIMG)
        acc += (double)__hip_atomic_load(&corr[t], __ATOMIC_ACQUIRE,
                                         __HIP_MEMORY_SCOPE_AGENT);
    sd[t] = acc;
    __syncthreads();
    for (int s = 128; s > 0; s >>= 1) {
        if (t < s) sd[t] += sd[t + s];
        __syncthreads();
    }
    if (t == 0) out[0] = (float)(-sd[0] / (double)NTOT);
}

extern "C" void kernel_launch(void* const* d_in, const int* in_sizes, int n_in,
                              void* d_out, int out_size, void* d_ws, size_t ws_size,
                              hipStream_t stream) {
    const float* pred = (const float*)d_in[0];
    float* out = (float*)d_out;

    char* ws = (char*)d_ws;
    int* L = (int*)ws;                                        // 33.5 MB
    int* edges = (int*)(ws + (size_t)NTOT * 4);               // 4 MB (4 dirs)
    int* cntArr = edges + 4 * EDGE2;                          // 8 KB
    int* maxArr = cntArr + NSCHUNK;                           // 8 KB
    int* minArr = maxArr + NSCHUNK;                           // 8 KB
    float* partials = (float*)(minArr + NSCHUNK);             // 8 KB (2048)
    float* corr = partials + NBLK2;                           // 128 B
    unsigned int* counter = (unsigned int*)(corr + NIMG);     // 4 B

    k_local<<<dim3(NBLK2), dim3(256), 0, stream>>>(pred, L, partials, edges, counter);
    k_border<<<dim3(NPAIR2 * 32 / 256), dim3(256), 0, stream>>>(edges, L);
    k_stats<<<dim3(NSCHUNK), dim3(256), 0, stream>>>(L, cntArr, maxArr, minArr);
    k_tail<<<dim3(NIMG), dim3(256), 0, stream>>>(cntArr, maxArr, minArr, L, pred,
                                                 partials, corr, counter, out);
}